// Round 13
// baseline (927.411 us; speedup 1.0000x reference)
//
#include <hip/hip_runtime.h>

#define TT 2048
#define II 8
#define HH 24
#define THRESH 0.1f
#define LOG2E 1.4426950408889634f

// rotate within 16-lane row by N, add (DPP row_ror, VALU-only)
#define ROR_ADD(a, N)                                                          \
    {                                                                          \
        int t_ = __builtin_amdgcn_update_dpp(0, __float_as_int(a),             \
                                             0x120 + (N), 0xF, 0xF, false);    \
        (a) += __int_as_float(t_);                                             \
    }

__device__ __forceinline__ float readlane_f(float v, int l) {
    return __int_as_float(__builtin_amdgcn_readlane(__float_as_int(v), l));
}

// One wave (= one block) per batch element; 2048 waves = 2 waves/SIMD.
//  lane l32=j<24, lo half : owns gate rows (i_j, f_j) — 2 full 32-wide dots
//  lane l32=j<24, hi half : owns gate rows (g_j, o_j)
//  other lanes            : junk (clamped row-0 weights), woutj=0 masks them
//
// R13: ZERO LDS. h-exchange via 24 v_readlane -> SGPRs (SALU pipe, ~2cy,
// no lgkmcnt); x rows are wave-uniform scalar loads (s_load) prefetched one
// step ahead — with no DS ops, lgkmcnt holds only the s_load, so the wait
// sits a full step downstream (R6's s_load/ds pollution mechanism is gone).
// Dot = v_fma(w_VGPR, v_SGPR, acc): 1 SGPR source per VALU op, no movs.
// Even/odd dual accumulators reproduce R9's v_pk_fma pairing bit-exactly.
__global__ __launch_bounds__(64)
__attribute__((amdgpu_waves_per_eu(2, 2)))
void lstm_anom_kernel(const float* __restrict__ x,
                      const float* __restrict__ W_ih,
                      const float* __restrict__ W_hh,
                      const float* __restrict__ b_ih,
                      const float* __restrict__ b_hh,
                      const float* __restrict__ W_out,
                      const float* __restrict__ b_out,
                      float* __restrict__ out)
{
    const int  lane  = threadIdx.x;
    const int  b     = blockIdx.x;
    const int  l32   = lane & 31;
    const bool hi    = lane >= 32;
    const bool unitL = (l32 < HH);
    const int  jc    = unitL ? l32 : 0;        // clamped for junk lanes

    const float* xb = x + (size_t)b * (TT * II);

    // ---- persistent weights: 2 full gate rows per lane (float4 chunks) ----
    const int rowA = (hi ? 2 * HH : 0) + jc;   // lo: i-gate, hi: g-gate
    const int rowB = rowA + HH;                // lo: f-gate, hi: o-gate
    float wA[32], wB[32];
    #pragma unroll
    for (int q = 0; q < 2; ++q) {              // W_ih rows: 8 floats
        const float4 qa = *(const float4*)(W_ih + rowA * II + q * 4);
        const float4 qb = *(const float4*)(W_ih + rowB * II + q * 4);
        wA[q*4+0]=qa.x; wA[q*4+1]=qa.y; wA[q*4+2]=qa.z; wA[q*4+3]=qa.w;
        wB[q*4+0]=qb.x; wB[q*4+1]=qb.y; wB[q*4+2]=qb.z; wB[q*4+3]=qb.w;
    }
    #pragma unroll
    for (int q = 0; q < 6; ++q) {              // W_hh rows: 24 floats
        const float4 qa = *(const float4*)(W_hh + rowA * HH + q * 4);
        const float4 qb = *(const float4*)(W_hh + rowB * HH + q * 4);
        wA[8+q*4+0]=qa.x; wA[8+q*4+1]=qa.y; wA[8+q*4+2]=qa.z; wA[8+q*4+3]=qa.w;
        wB[8+q*4+0]=qb.x; wB[8+q*4+1]=qb.y; wB[8+q*4+2]=qb.z; wB[8+q*4+3]=qb.w;
    }
    const float biasA = b_ih[rowA] + b_hh[rowA];
    const float biasB = b_ih[rowB] + b_hh[rowB];
    // nonlin A: lo -> sigmoid(a), hi -> tanh(a) = 2*sigmoid(2a)-1, uniform code
    const float kA = hi ? (-2.f * LOG2E) : (-LOG2E);
    const float mA = hi ? 2.f : 1.f;
    const float nA = hi ? -1.f : 0.f;
    const float woutj = unitL ? W_out[jc] : 0.f;
    const float bout  = b_out[0];

    // ---- uniform state: current x row (SGPRs) + h (SGPRs via readlane) ----
    float cx[8], nx[8], sh[HH];
    #pragma unroll
    for (int k = 0; k < 8; ++k) cx[k] = xb[k];      // row 0, uniform -> s_load
    #pragma unroll
    for (int j = 0; j < HH; ++j) sh[j] = 0.f;       // h0 = 0

    float pred = cx[0];        // pred0 = x[b][0][0] -> no substitution at t=0
    float cst = 0.f, predsave = 0.f;

    for (int t = 0; t < TT; ++t) {
        // ---- prefetch next x row (uniform scalar loads, one step of slack)
        const int tn = (t + 1 < TT) ? (t + 1) : (TT - 1);
        #pragma unroll
        for (int k = 0; k < 8; ++k) nx[k] = xb[(size_t)tn * II + k];

        // ---- anomaly substitution on input 0 (VALU, then feeds fma as VGPR)
        const float v0 = (fabsf(pred - cx[0]) > THRESH) ? pred : cx[0];

        // ---- 2 full 32-wide gate dots; even/odd accs == R9's pk pairing ----
        float aAx = fmaf(wA[0], v0, biasA), aAy = wA[1] * cx[1];
        float aBx = fmaf(wB[0], v0, biasB), aBy = wB[1] * cx[1];
        #pragma unroll
        for (int k = 1; k < 4; ++k) {
            aAx = fmaf(wA[2*k],   cx[2*k],   aAx);
            aAy = fmaf(wA[2*k+1], cx[2*k+1], aAy);
            aBx = fmaf(wB[2*k],   cx[2*k],   aBx);
            aBy = fmaf(wB[2*k+1], cx[2*k+1], aBy);
        }
        #pragma unroll
        for (int k = 0; k < 12; ++k) {
            aAx = fmaf(wA[8+2*k],   sh[2*k],   aAx);
            aAy = fmaf(wA[8+2*k+1], sh[2*k+1], aAy);
            aBx = fmaf(wB[8+2*k],   sh[2*k],   aBx);
            aBy = fmaf(wB[8+2*k+1], sh[2*k+1], aBy);
        }
        const float aA = aAx + aAy;
        const float aB = aBx + aBy;

        // ---- nonlinearities, once per gate ----
        const float sA = __builtin_amdgcn_rcpf(1.f + __builtin_amdgcn_exp2f(kA * aA));
        const float tA = fmaf(sA, mA, nA);                  // lo: sig(i), hi: tanh(g)
        const float sB = __builtin_amdgcn_rcpf(1.f + __builtin_amdgcn_exp2f(-LOG2E * aB));
                                                            // lo: sig(f), hi: sig(o)
        // ---- distribute halves: every lane gets (ig,gg,fg,og) ----
        auto rA = __builtin_amdgcn_permlane32_swap(__float_as_int(tA), __float_as_int(tA), false, false);
        auto rB = __builtin_amdgcn_permlane32_swap(__float_as_int(sB), __float_as_int(sB), false, false);
        const float ig = __int_as_float(rA[0]);
        const float gg = __int_as_float(rA[1]);
        const float fg = __int_as_float(rB[0]);
        const float og = __int_as_float(rB[1]);

        cst = fmaf(fg, cst, ig * gg);
        const float sc = __builtin_amdgcn_rcpf(1.f + __builtin_amdgcn_exp2f(-2.f * LOG2E * cst));
        const float tc = fmaf(2.f, sc, -1.f);               // tanh(c)
        const float h  = og * tc;

        // ---- h exchange: 24 readlanes -> SGPRs (SALU pipe, no memory) ----
        #pragma unroll
        for (int j = 0; j < HH; ++j) sh[j] = readlane_f(h, j);

        // ---- head: Σ_j wout_j*h_j (permlane16 fold + 4 DPP ror-adds) ----
        float p = woutj * h;
        {
            auto r = __builtin_amdgcn_permlane16_swap(__float_as_int(p), __float_as_int(p), false, false);
            p = __int_as_float(r[0]) + __int_as_float(r[1]);
        }
        ROR_ADD(p, 8); ROR_ADD(p, 4); ROR_ADD(p, 2); ROR_ADD(p, 1);
        pred = p + bout;

        // buffer pred; coalesced 256B flush every 64 steps
        predsave = ((t & 63) == lane) ? pred : predsave;
        if ((t & 63) == 63) out[(size_t)b * TT + (t - 63) + lane] = predsave;

        // ---- rotate x prefetch ----
        #pragma unroll
        for (int k = 0; k < 8; ++k) cx[k] = nx[k];
    }
}

extern "C" void kernel_launch(void* const* d_in, const int* in_sizes, int n_in,
                              void* d_out, int out_size, void* d_ws, size_t ws_size,
                              hipStream_t stream) {
    const float* x     = (const float*)d_in[0];
    const float* W_ih  = (const float*)d_in[1];
    const float* W_hh  = (const float*)d_in[2];
    const float* b_ih  = (const float*)d_in[3];
    const float* b_hh  = (const float*)d_in[4];
    const float* W_out = (const float*)d_in[5];
    const float* b_out = (const float*)d_in[6];
    float* out = (float*)d_out;

    dim3 grid(2048);   // one wave per batch element
    dim3 block(64);
    lstm_anom_kernel<<<grid, block, 0, stream>>>(x, W_ih, W_hh, b_ih, b_hh,
                                                 W_out, b_out, out);
}